// Round 17
// baseline (330.289 us; speedup 1.0000x reference)
//
#include <hip/hip_runtime.h>

typedef unsigned int uint;
typedef unsigned short ushort;

typedef __attribute__((ext_vector_type(8))) short bf8;
typedef __attribute__((ext_vector_type(4))) float f32x4;
typedef _Float16 half_t;
typedef __attribute__((ext_vector_type(8))) half_t h8;

__device__ __forceinline__ ushort f2bf(float f){
  uint u = __builtin_bit_cast(uint, f);
  u = u + 0x7FFFu + ((u >> 16) & 1u);
  return (ushort)(u >> 16);
}
__device__ __forceinline__ float bfl(uint u){ return __builtin_bit_cast(float, u << 16); }
__device__ __forceinline__ float bfh(uint u){ return __builtin_bit_cast(float, u & 0xFFFF0000u); }
__device__ __forceinline__ uint pkhalf(float a, float b){
  ushort lo = __builtin_bit_cast(ushort, (half_t)a);
  ushort hi = __builtin_bit_cast(ushort, (half_t)b);
  return (uint)lo | ((uint)hi << 16);
}
__device__ __forceinline__ float sigmoidf_(float x){ return 1.0f/(1.0f + __expf(-x)); }
// tanh(x) = 2*sigma(2x) - 1 : 5 VALU ops, NaN-safe at both infinities (no clamp).
__device__ __forceinline__ float tanhf_(float x){
  return 2.0f/(1.0f + __expf(-2.0f*x)) - 1.0f;
}
__device__ __forceinline__ f32x4 mfma_f16(h8 a, h8 b, f32x4 c){
  return __builtin_amdgcn_mfma_f32_16x16x32_f16(a, b, c, 0, 0, 0);
}
__device__ __forceinline__ f32x4 mfma_bf(bf8 a, bf8 b, f32x4 c){
  return __builtin_amdgcn_mfma_f32_16x16x32_bf16(a, b, c, 0, 0, 0);
}
__device__ __forceinline__ h8 ldw8(const float* p){
  f32x4 a = *(const f32x4*)p, b = *(const f32x4*)(p+4);
  h8 v;
  #pragma unroll
  for (int j=0;j<4;j++){ v[j] = (half_t)a[j]; v[4+j] = (half_t)b[j]; }
  return v;
}

// ---- fused prep + weight-convert + EF table --------------------------------------
__global__ __launch_bounds__(256) void k_prep(const float* __restrict__ x,
    const int* __restrict__ dst,
    int* __restrict__ typ, int* __restrict__ mlist, int* __restrict__ cnt,
    int* __restrict__ deg, float* __restrict__ Hf, ushort* __restrict__ Hb,
    const float* wq, const float* wk, const float* wv,
    const float* w1, const float* w2, const float* wih, const float* whh,
    const float* __restrict__ op_emb,
    ushort* oqkv, ushort* o1, ushort* o2, ushort* oih, ushort* ohh,
    ushort* __restrict__ EF,
    int N, int E){
  int i = blockIdx.x*256 + threadIdx.x;
  int total = gridDim.x*256;
  if (i < N){
    const float* xr = x + (size_t)i*16;
    int t = 0;
    #pragma unroll
    for (int j=0;j<16;j++) if (xr[j] > 0.5f) t = j;
    typ[i] = t;
    if (t < 2){
      int p = atomicAdd(cnt, 1);
      mlist[p] = i;
    }
  }
  if (i < E) atomicAdd(&deg[dst[i]], 1);
  f32x4 z4 = (f32x4)0.0f;
  for (int j = i; j < N*32; j += total) ((f32x4*)Hf)[j] = z4;
  uint2 z2; z2.x = 0u; z2.y = 0u;
  for (int j = i; j < N*32; j += total) ((uint2*)Hb)[j] = z2;
  for (int j=i; j<16384; j+=total){
    oqkv[j]       = f2bf(wq[j]);
    oqkv[16384+j] = f2bf(wk[j]);
    oqkv[32768+j] = f2bf(wv[j]);
    o1[j] = f2bf(w1[j]);
    o2[j] = f2bf(w2[j]);
  }
  for (int j=i; j<49152; j+=total){ oih[j]=f2bf(wih[j]); ohh[j]=f2bf(whh[j]); }
  for (int idx=i; idx<512*128; idx+=total){
    int r = idx >> 7, d = idx & 127;
    int et = r >> 4, op = r & 15;
    int j = d >> 1;
    float inv = __expf(-0.1439115683f * (float)j);   // 10000^(-j/64)
    float ang = (float)et * inv;
    float v = (d & 1) ? __cosf(ang) : __sinf(ang);
    EF[idx] = f2bf(v + op_emb[op*128 + d]);
  }
}

// ---- generic bf16 MFMA GEMM: C[M,N] = act(A[M,128] @ B[N,128]^T + bias) --------
template<int RELU, int HASBIAS>
__global__ __launch_bounds__(256) void k_gemm(
    const ushort* __restrict__ A, const ushort* __restrict__ B,
    const float* __restrict__ bias, ushort* __restrict__ C, int M, int N){
  int lane = threadIdx.x & 63, wv = threadIdx.x >> 6;
  int tM = blockIdx.x*64 + (wv>>1)*32;
  int tN = blockIdx.y*64 + (wv&1)*32;
  int r16 = lane & 15, kg = (lane>>4)*8;
  f32x4 acc[2][2];
  #pragma unroll
  for (int i=0;i<2;i++)
    #pragma unroll
    for (int j=0;j<2;j++) acc[i][j] = (f32x4)0.0f;
  #pragma unroll
  for (int k0=0;k0<128;k0+=32){
    bf8 a[2], b[2];
    #pragma unroll
    for (int i=0;i<2;i++){
      int row = tM + i*16 + r16; if (row > M-1) row = M-1;
      a[i] = *(const bf8*)(A + (size_t)row*128 + k0 + kg);
    }
    #pragma unroll
    for (int j=0;j<2;j++){
      int col = tN + j*16 + r16;
      b[j] = *(const bf8*)(B + (size_t)col*128 + k0 + kg);
    }
    #pragma unroll
    for (int i=0;i<2;i++)
      #pragma unroll
      for (int j=0;j<2;j++)
        acc[i][j] = __builtin_amdgcn_mfma_f32_16x16x32_bf16(a[i], b[j], acc[i][j], 0, 0, 0);
  }
  #pragma unroll
  for (int i=0;i<2;i++)
    #pragma unroll
    for (int j=0;j<2;j++){
      int col = tN + j*16 + r16;
      float bs = HASBIAS ? bias[col] : 0.0f;
      #pragma unroll
      for (int q=0;q<4;q++){
        int row = tM + i*16 + (lane>>4)*4 + q;
        if (row < M){
          float v = acc[i][j][q] + bs;
          if (RELU) v = fmaxf(v, 0.0f);
          C[(size_t)row*N + col] = f2bf(v);
        }
      }
    }
}

// ---- pipelined swapped-MFMA 2-layer GRU encoder (f16 x-staging) -----------------
__global__ __launch_bounds__(512, 1) void k_enc4(
    const float* __restrict__ sim_res, const int* __restrict__ seqlen,
    const float* __restrict__ Wih0, const float* __restrict__ Whh0,
    const float* __restrict__ bih0, const float* __restrict__ bhh0,
    const float* __restrict__ Wih1, const float* __restrict__ Whh1,
    const float* __restrict__ bih1, const float* __restrict__ bhh1,
    const int* __restrict__ mlist, const int* __restrict__ cntp,
    float* __restrict__ Hf, ushort* __restrict__ Hb){
  int C = *cntp;
  int base = blockIdx.x * 16;
  if (C == 0 || base >= C) return;
  int tid = threadIdx.x;
  int w = tid >> 6, l = tid & 63;
  int node = l & 15, hi = l >> 4;
  int grp = w >> 2;          // 0 = layer 0 group, 1 = layer 1 group
  int ws  = w & 3;           // hidden-slice owner within group

  __shared__ int nod[16];
  __shared__ __align__(16) ushort Xh[16*32*32];               // f16, 32 KB
  __shared__ __align__(16) ushort H0h[2][16*64], H1h[2][16*64];

  if (tid < 16){
    int idx = base + tid;
    nod[tid] = mlist[idx < C ? idx : C-1];
  }
  for (int i = tid; i < 16*64; i += 512){
    H0h[0][i] = 0; H0h[1][i] = 0; H1h[0][i] = 0; H1h[1][i] = 0;
  }
  __syncthreads();   // nod ready

  // stage x as f16: 2048 chunks of 16B. chunk m = [node(4b)][t(5b)][c(2b)];
  // LDS logical chunk c holds source chunk c^(node&3).
  for (int m = tid; m < 2048; m += 512){
    int nm = m >> 7, rem = m & 127, tt = rem >> 2, c = rem & 3;
    int cs = c ^ (nm & 3);
    const float* s = sim_res + (size_t)nod[nm]*1024 + tt*32 + cs*8;
    f32x4 a = *(const f32x4*)s, b = *(const f32x4*)(s+4);
    h8 v;
    #pragma unroll
    for (int j=0;j<4;j++){ v[j] = (half_t)a[j]; v[4+j] = (half_t)b[j]; }
    *(h8*)((char*)Xh + m*16) = v;
  }

  int rr = 16*ws + node;
  h8 zf;
  #pragma unroll
  for (int j=0;j<8;j++) zf[j] = (half_t)0.f;
  h8 Ai_r[2] = {zf, zf}, Ai_z[2] = {zf, zf}, Ai_n[2] = {zf, zf};
  h8 Ah_r[2], Ah_z[2], Ah_n[2];
  if (grp == 0){
    Ai_r[0] = ldw8(Wih0 + (size_t)rr*32        + hi*8);
    Ai_z[0] = ldw8(Wih0 + (size_t)(64+rr)*32   + hi*8);
    Ai_n[0] = ldw8(Wih0 + (size_t)(128+rr)*32  + hi*8);
    #pragma unroll
    for (int s=0;s<2;s++){
      Ah_r[s] = ldw8(Whh0 + (size_t)rr*64       + s*32 + hi*8);
      Ah_z[s] = ldw8(Whh0 + (size_t)(64+rr)*64  + s*32 + hi*8);
      Ah_n[s] = ldw8(Whh0 + (size_t)(128+rr)*64 + s*32 + hi*8);
    }
  } else {
    #pragma unroll
    for (int s=0;s<2;s++){
      Ai_r[s] = ldw8(Wih1 + (size_t)rr*64       + s*32 + hi*8);
      Ai_z[s] = ldw8(Wih1 + (size_t)(64+rr)*64  + s*32 + hi*8);
      Ai_n[s] = ldw8(Wih1 + (size_t)(128+rr)*64 + s*32 + hi*8);
      Ah_r[s] = ldw8(Whh1 + (size_t)rr*64       + s*32 + hi*8);
      Ah_z[s] = ldw8(Whh1 + (size_t)(64+rr)*64  + s*32 + hi*8);
      Ah_n[s] = ldw8(Whh1 + (size_t)(128+rr)*64 + s*32 + hi*8);
    }
  }
  const float* bi = grp ? bih1 : bih0;
  const float* bh = grp ? bhh1 : bhh0;
  float br[4], bz[4], bni[4], bnh[4];
  #pragma unroll
  for (int q=0;q<4;q++){
    int row = 16*ws + hi*4 + q;
    br[q]  = bi[row]      + bh[row];
    bz[q]  = bi[64+row]   + bh[64+row];
    bni[q] = bi[128+row];
    bnh[q] = bh[128+row];
  }

  int T = *seqlen; if (T > 32) T = 32; if (T < 0) T = 0;
  float hm[4] = {0.f, 0.f, 0.f, 0.f};

  const int swz = (node & 7) << 4;
  const int wo  = node * 128;
  const int wba = 32*ws + 8*hi;
  const int rd0 = wo + ((16*hi) ^ swz);
  const int rd1 = wo + ((64 + 16*hi) ^ swz);
  const int xoff = node*2048 + ((hi*16) ^ ((node & 3) << 4));  // byte offset; + t*64
  const char* xbase = (const char*)Xh;

  __syncthreads();   // Xh + zeroed state buffers ready

  for (int k = 0; k <= T; ++k){
    int cur = k & 1;
    bool act = grp ? (k >= 1) : (k < T);
    if (act){
      h8 in0 = zf, in1 = zf, st0, st1;
      if (grp == 0){
        in0 = *(const h8*)(xbase + xoff + k*64);
        st0 = *(const h8*)((const char*)H0h[cur] + rd0);
        st1 = *(const h8*)((const char*)H0h[cur] + rd1);
      } else {
        in0 = *(const h8*)((const char*)H0h[cur] + rd0);
        in1 = *(const h8*)((const char*)H0h[cur] + rd1);
        st0 = *(const h8*)((const char*)H1h[cur] + rd0);
        st1 = *(const h8*)((const char*)H1h[cur] + rd1);
      }
      f32x4 ar = {br[0],br[1],br[2],br[3]};
      f32x4 az = {bz[0],bz[1],bz[2],bz[3]};
      f32x4 an = {bni[0],bni[1],bni[2],bni[3]};
      f32x4 hn = {bnh[0],bnh[1],bnh[2],bnh[3]};
      __builtin_amdgcn_s_setprio(1);
      ar = mfma_f16(Ai_r[0], in0, ar);
      az = mfma_f16(Ai_z[0], in0, az);
      an = mfma_f16(Ai_n[0], in0, an);
      if (grp){
        ar = mfma_f16(Ai_r[1], in1, ar);
        az = mfma_f16(Ai_z[1], in1, az);
        an = mfma_f16(Ai_n[1], in1, an);
      }
      ar = mfma_f16(Ah_r[0], st0, ar); ar = mfma_f16(Ah_r[1], st1, ar);
      az = mfma_f16(Ah_z[0], st0, az); az = mfma_f16(Ah_z[1], st1, az);
      hn = mfma_f16(Ah_n[0], st0, hn); hn = mfma_f16(Ah_n[1], st1, hn);
      __builtin_amdgcn_s_setprio(0);
      #pragma unroll
      for (int q=0;q<4;q++){
        float r = sigmoidf_(ar[q]);
        float z = sigmoidf_(az[q]);
        float n = tanhf_(an[q] + r*hn[q]);
        hm[q] = (1.f - z)*n + z*hm[q];
      }
      char* outb = grp ? (char*)H1h[cur^1] : (char*)H0h[cur^1];
      *(uint*)(outb + wo + ( wba      ^ swz)) = pkhalf(hm[0], hm[1]);
      *(uint*)(outb + wo + ((wba + 4) ^ swz)) = pkhalf(hm[2], hm[3]);
    }
    __syncthreads();
  }

  if (base + node < C){
    int nd = nod[node];
    int off = grp ? 64 : 0;
    #pragma unroll
    for (int q=0;q<4;q++){
      int j = off + 16*ws + hi*4 + q;
      Hf[(size_t)nd*128 + j] = hm[q];
      Hb[(size_t)nd*128 + j] = f2bf(hm[q]);
    }
  }
}

// ---- CSR scan: thread-coarsened single pass (1 barrier) ---------------------------
__global__ __launch_bounds__(1024) void k_scan(const int* __restrict__ deg,
    int* __restrict__ rowptr, int* __restrict__ cursor, int N){
  __shared__ int wsum[16];
  int tid = threadIdx.x, lane = tid & 63, wid = tid >> 6;
  int CH = (N + 1023) >> 10;
  int start = tid * CH;
  int local = 0;
  for (int j=0;j<CH;j++){ int i = start+j; if (i < N) local += deg[i]; }
  int x = local;
  #pragma unroll
  for (int off=1; off<64; off<<=1){
    int t = __shfl_up(x, off, 64);
    if (lane >= off) x += t;
  }
  if (lane == 63) wsum[wid] = x;
  __syncthreads();
  int woff = 0;
  for (int w2=0; w2<wid; ++w2) woff += wsum[w2];
  int run = woff + x - local;
  for (int j=0;j<CH;j++){
    int i = start+j;
    if (i < N){ rowptr[i] = run; cursor[i] = run; run += deg[i]; }
  }
  if (tid == 1023) rowptr[N] = run;
}

__global__ __launch_bounds__(256) void k_scatter(const int* __restrict__ src,
    const int* __restrict__ dst, const int* __restrict__ etype, const int* __restrict__ typ,
    int* __restrict__ cursor, int* __restrict__ es_src, int* __restrict__ es_tab, int E){
  int e = blockIdx.x*256 + threadIdx.x;
  if (e < E){
    int d = dst[e];
    int pos = atomicAdd(&cursor[d], 1);
    es_src[pos] = src[e];
    es_tab[pos] = etype[e]*16 + typ[d];
  }
}

// ---- attention: one wave per dst node, online softmax, 4-edge unrolled -----------
__global__ __launch_bounds__(256) void k_attn(
    const uint* __restrict__ QKV, const uint* __restrict__ KVT,
    const int* __restrict__ rowptr, const int* __restrict__ es_src, const int* __restrict__ es_tab,
    uint* __restrict__ aggr, int N){
  int w = threadIdx.x >> 6, lane = threadIdx.x & 63;
  int dst = blockIdx.x*4 + w;
  if (dst >= N) return;
  uint qu = QKV[(size_t)dst*192 + lane];
  const float scale = 0.08838834764831845f;  // 1/sqrt(128)
  float q0 = bfl(qu)*scale, q1 = bfh(qu)*scale;
  int s0 = rowptr[dst], s1 = rowptr[dst+1];
  float m = -1e30f, den = 0.f, a0 = 0.f, a1 = 0.f;
  int p = s0;
  for (; p + 4 <= s1; p += 4){
    int se[4], te[4];
    #pragma unroll
    for (int e=0;e<4;e++){ se[e] = es_src[p+e]; te[e] = es_tab[p+e]; }
    uint ku[4], kt[4], vu[4], vt[4];
    #pragma unroll
    for (int e=0;e<4;e++){
      ku[e] = QKV[(size_t)se[e]*192 + 64 + lane];
      kt[e] = KVT[(size_t)te[e]*128 + lane];
      vu[e] = QKV[(size_t)se[e]*192 + 128 + lane];
      vt[e] = KVT[(size_t)te[e]*128 + 64 + lane];
    }
    float s[4];
    #pragma unroll
    for (int e=0;e<4;e++)
      s[e] = q0*(bfl(ku[e])+bfl(kt[e])) + q1*(bfh(ku[e])+bfh(kt[e]));
    #pragma unroll
    for (int off=32; off; off>>=1){
      #pragma unroll
      for (int e=0;e<4;e++) s[e] += __shfl_xor(s[e], off);
    }
    float nm = fmaxf(fmaxf(m, fmaxf(s[0], s[1])), fmaxf(s[2], s[3]));
    float c  = __expf(m - nm);
    float pw[4];
    #pragma unroll
    for (int e=0;e<4;e++) pw[e] = __expf(s[e] - nm);
    den = den*c + pw[0] + pw[1] + pw[2] + pw[3];
    a0 = a0*c; a1 = a1*c;
    #pragma unroll
    for (int e=0;e<4;e++){
      a0 += pw[e]*(bfl(vu[e])+bfl(vt[e]));
      a1 += pw[e]*(bfh(vu[e])+bfh(vt[e]));
    }
    m = nm;
  }
  for (; p < s1; ++p){
    int src = es_src[p], tb = es_tab[p];
    uint ku = QKV[(size_t)src*192 + 64 + lane],  kt = KVT[(size_t)tb*128 + lane];
    uint vu = QKV[(size_t)src*192 + 128 + lane], vt = KVT[(size_t)tb*128 + 64 + lane];
    float s = q0*(bfl(ku)+bfl(kt)) + q1*(bfh(ku)+bfh(kt));
    #pragma unroll
    for (int off=32; off; off>>=1) s += __shfl_xor(s, off);
    float nm = fmaxf(m, s);
    float c  = __expf(m - nm);
    float pw = __expf(s - nm);
    den = den*c + pw;
    a0  = a0*c + pw*(bfl(vu)+bfl(vt));
    a1  = a1*c + pw*(bfh(vu)+bfh(vt));
    m = nm;
  }
  float inv = 1.0f/(den + 1e-9f);
  a0 *= inv; a1 *= inv;
  aggr[(size_t)dst*64 + lane] = ((uint)f2bf(a1) << 16) | (uint)f2bf(a0);
}

// ---- fused MLP1 + MLP2 + GRU cell — 16 nodes/block, 8 waves × 16 cols -------------
// Grid doubled to 1250 blocks (~4 co-resident blocks/CU) to lift occupancy;
// per-block critical path halved. Weights are L2-resident so the 2× weight
// re-read across blocks is ~free.
// NOTE: Hbf aliases Hb_out, Hf_in may alias Hf_out — no __restrict__ on those.
__global__ __launch_bounds__(512, 2) void k_fused(
    const ushort* __restrict__ Ag,
    const ushort* __restrict__ W1b, const float* __restrict__ b1,
    const ushort* __restrict__ W2b, const float* __restrict__ b2,
    const ushort* __restrict__ Wih, const ushort* __restrict__ Whh,
    const float* __restrict__ bih, const float* __restrict__ bhh,
    const ushort* Hbf, const float* Hf_in,
    float* Hf_out, ushort* Hb_out, int M){
  int lane = threadIdx.x & 63, w = threadIdx.x >> 6;   // w: 0..7, 16 cols each
  int nb = blockIdx.x * 16;
  int r16 = lane & 15, kq = lane >> 4;
  const int col = w*16 + r16;                          // 0..127

  __shared__ __align__(16) ushort T[16*128];   // 4 KB swizzled intermediate

  // entry loads (A-operands shared across phases)
  bf8 agld[4], ahld[4];
  {
    int grow = nb + r16; if (grow > M-1) grow = M-1;
    #pragma unroll
    for (int ks=0;ks<4;ks++){
      agld[ks] = *(const bf8*)(Ag  + (size_t)grow*128 + ks*32 + kq*8);
      ahld[ks] = *(const bf8*)(Hbf + (size_t)grow*128 + ks*32 + kq*8);
    }
  }
  float hprev[4];
  #pragma unroll
  for (int q=0;q<4;q++){
    int node = nb + kq*4 + q;
    hprev[q] = Hf_in[(size_t)(node < M ? node : M-1)*128 + col];
  }

  // ---------- phase 1: T = relu(Ag @ W1^T + b1) ----------
  {
    f32x4 a0 = (f32x4)0.0f;
    #pragma unroll
    for (int ks=0; ks<4; ++ks){
      bf8 wb = *(const bf8*)(W1b + (size_t)col*128 + ks*32 + kq*8);
      a0 = mfma_bf(agld[ks], wb, a0);
    }
    float bs = b1[col];
    #pragma unroll
    for (int q=0;q<4;q++){
      int row = kq*4 + q;
      *(ushort*)((char*)T + ((row*256 + col*2) ^ ((row&7)<<4))) = f2bf(fmaxf(a0[q] + bs, 0.0f));
    }
  }
  __syncthreads();

  // ---------- phase 2: X = T @ W2^T + b2 ----------
  {
    f32x4 a0 = (f32x4)0.0f;
    #pragma unroll
    for (int ks=0; ks<4; ++ks){
      bf8 wb = *(const bf8*)(W2b + (size_t)col*128 + ks*32 + kq*8);
      int row = r16;
      bf8 ax = *(const bf8*)((const char*)T + row*256 + ((ks*64 + kq*16) ^ ((row&7)<<4)));
      a0 = mfma_bf(ax, wb, a0);
    }
    __syncthreads();   // all T reads complete before overwrite
    float bs = b2[col];
    #pragma unroll
    for (int q=0;q<4;q++){
      int row = kq*4 + q;
      *(ushort*)((char*)T + ((row*256 + col*2) ^ ((row&7)<<4))) = f2bf(a0[q] + bs);
    }
  }
  __syncthreads();

  // ---------- phase 3: GRU gates ----------
  f32x4 ar = (f32x4)0.0f, az = (f32x4)0.0f, ani = (f32x4)0.0f, anh = (f32x4)0.0f;
  #pragma unroll
  for (int ks=0; ks<4; ++ks){
    int off = ks*32 + kq*8;
    bf8 wri = *(const bf8*)(Wih + (size_t)col*128       + off);
    bf8 wrh = *(const bf8*)(Whh + (size_t)col*128       + off);
    bf8 wzi = *(const bf8*)(Wih + (size_t)(128+col)*128 + off);
    bf8 wzh = *(const bf8*)(Whh + (size_t)(128+col)*128 + off);
    bf8 wni = *(const bf8*)(Wih + (size_t)(256+col)*128 + off);
    bf8 wnh = *(const bf8*)(Whh + (size_t)(256+col)*128 + off);
    int row = r16;
    bf8 ax = *(const bf8*)((const char*)T + row*256 + ((ks*64 + kq*16) ^ ((row&7)<<4)));
    ar  = mfma_bf(ax,       wri, ar);
    ar  = mfma_bf(ahld[ks], wrh, ar);
    az  = mfma_bf(ax,       wzi, az);
    az  = mfma_bf(ahld[ks], wzh, az);
    ani = mfma_bf(ax,       wni, ani);
    anh = mfma_bf(ahld[ks], wnh, anh);
  }
  // epilogue: gates + in-lane h update
  float br_  = bih[col]     + bhh[col];
  float bz_  = bih[128+col] + bhh[128+col];
  float bni_ = bih[256+col];
  float bnh_ = bhh[256+col];
  #pragma unroll
  for (int q=0;q<4;q++){
    int node = nb + kq*4 + q;
    if (node < M){
      float r = sigmoidf_(ar[q] + br_);
      float z = sigmoidf_(az[q] + bz_);
      float n = tanhf_(ani[q] + bni_ + r*(anh[q] + bnh_));
      float h = hprev[q];
      float o = (1.f - z)*n + z*h;
      Hf_out[(size_t)node*128 + col] = o;
      Hb_out[(size_t)node*128 + col] = f2bf(o);
    }
  }
}

extern "C" void kernel_launch(void* const* d_in, const int* in_sizes, int n_in,
                              void* d_out, int out_size, void* d_ws, size_t ws_size,
                              hipStream_t stream){
  const float* x       = (const float*)d_in[0];
  const int*   ei      = (const int*)d_in[1];
  const int*   etype   = (const int*)d_in[2];
  const float* sim_res = (const float*)d_in[3];
  const int*   seqlen  = (const int*)d_in[4];
  const float* eWih0 = (const float*)d_in[5];
  const float* eWhh0 = (const float*)d_in[6];
  const float* ebih0 = (const float*)d_in[7];
  const float* ebhh0 = (const float*)d_in[8];
  const float* eWih1 = (const float*)d_in[9];
  const float* eWhh1 = (const float*)d_in[10];
  const float* ebih1 = (const float*)d_in[11];
  const float* ebhh1 = (const float*)d_in[12];
  const float* Wq = (const float*)d_in[13];
  const float* Wk = (const float*)d_in[14];
  const float* Wv = (const float*)d_in[15];
  const float* op_emb = (const float*)d_in[16];
  const float* W1 = (const float*)d_in[17];
  const float* b1 = (const float*)d_in[18];
  const float* W2 = (const float*)d_in[19];
  const float* b2 = (const float*)d_in[20];
  const float* gWih = (const float*)d_in[21];
  const float* gWhh = (const float*)d_in[22];
  const float* gbih = (const float*)d_in[23];
  const float* gbhh = (const float*)d_in[24];

  const int N = in_sizes[0] / 16;
  const int E = in_sizes[2];

  char* p = (char*)d_ws;
  auto take = [&](size_t b)->void*{ void* r = (void*)p; p += (b + 255) & ~(size_t)255; return r; };

  float*  Hf    = (float*) take((size_t)N*128*4);
  ushort* Hb    = (ushort*)take((size_t)N*128*2);
  ushort* QKV   = (ushort*)take((size_t)N*384*2);
  ushort* Ag    = (ushort*)take((size_t)N*128*2);
  ushort* EF    = (ushort*)take((size_t)512*128*2);
  ushort* KVtab = (ushort*)take((size_t)512*256*2);
  ushort* wqkv  = (ushort*)take((size_t)3*16384*2);   // [wq | wk | wv] rows
  ushort* w1_b  = (ushort*)take((size_t)16384*2);
  ushort* w2_b  = (ushort*)take((size_t)16384*2);
  ushort* wih_b = (ushort*)take((size_t)49152*2);
  ushort* whh_b = (ushort*)take((size_t)49152*2);
  int* typ    = (int*)take((size_t)N*4);
  int* mlist  = (int*)take((size_t)N*4);
  int* cnt    = (int*)take(256);
  int* deg    = (int*)take((size_t)N*4);
  int* rowptr = (int*)take((size_t)(N+1)*4);
  int* cursor = (int*)take((size_t)N*4);
  int* es_src = (int*)take((size_t)E*4);
  int* es_tab = (int*)take((size_t)E*4);

  hipMemsetAsync(cnt, 0, 4, stream);
  hipMemsetAsync(deg, 0, (size_t)N*4, stream);

  int gE = (E + 255) / 256;
  k_prep<<<gE, 256, 0, stream>>>(x, ei + E, typ, mlist, cnt, deg, Hf, Hb,
                                 Wq, Wk, Wv, W1, W2, gWih, gWhh, op_emb,
                                 wqkv, w1_b, w2_b, wih_b, whh_b, EF, N, E);
  k_gemm<0,0><<<dim3(8,4), 256, 0, stream>>>(EF, wqkv + 16384, nullptr, KVtab, 512, 256);
  k_enc4<<<(N+15)/16, 512, 0, stream>>>(sim_res, seqlen, eWih0, eWhh0, ebih0, ebhh0,
                                        eWih1, eWhh1, ebih1, ebhh1, mlist, cnt, Hf, Hb);
  k_scan<<<1, 1024, 0, stream>>>(deg, rowptr, cursor, N);
  k_scatter<<<gE, 256, 0, stream>>>(ei, ei + E, etype, typ, cursor, es_src, es_tab, E);

  dim3 gq((N+63)/64, 6);   // fused QKV: N_out = 384
  for (int r=0; r<2; ++r){
    k_gemm<0,0><<<gq, 256, 0, stream>>>(Hb, wqkv, nullptr, QKV, N, 384);
    k_attn<<<(N+3)/4, 256, 0, stream>>>((const uint*)QKV, (const uint*)KVtab,
                                        rowptr, es_src, es_tab, (uint*)Ag, N);
    float* hf_out = (r == 1) ? (float*)d_out : Hf;
    k_fused<<<(N+15)/16, 512, 0, stream>>>(Ag, w1_b, b1, w2_b, b2,
                                           wih_b, whh_b, gbih, gbhh,
                                           Hb, Hf, hf_out, Hb, N);
  }
}

// Round 18
// 313.203 us; speedup vs baseline: 1.0546x; 1.0546x over previous
//
#include <hip/hip_runtime.h>

typedef unsigned int uint;
typedef unsigned short ushort;

typedef __attribute__((ext_vector_type(8))) short bf8;
typedef __attribute__((ext_vector_type(4))) float f32x4;
typedef _Float16 half_t;
typedef __attribute__((ext_vector_type(8))) half_t h8;

__device__ __forceinline__ ushort f2bf(float f){
  uint u = __builtin_bit_cast(uint, f);
  u = u + 0x7FFFu + ((u >> 16) & 1u);
  return (ushort)(u >> 16);
}
__device__ __forceinline__ float bfl(uint u){ return __builtin_bit_cast(float, u << 16); }
__device__ __forceinline__ float bfh(uint u){ return __builtin_bit_cast(float, u & 0xFFFF0000u); }
__device__ __forceinline__ uint pkhalf(float a, float b){
  ushort lo = __builtin_bit_cast(ushort, (half_t)a);
  ushort hi = __builtin_bit_cast(ushort, (half_t)b);
  return (uint)lo | ((uint)hi << 16);
}
__device__ __forceinline__ float sigmoidf_(float x){ return 1.0f/(1.0f + __expf(-x)); }
// tanh(x) = 2*sigma(2x) - 1 : 5 VALU ops, NaN-safe at both infinities (no clamp).
__device__ __forceinline__ float tanhf_(float x){
  return 2.0f/(1.0f + __expf(-2.0f*x)) - 1.0f;
}
__device__ __forceinline__ f32x4 mfma_f16(h8 a, h8 b, f32x4 c){
  return __builtin_amdgcn_mfma_f32_16x16x32_f16(a, b, c, 0, 0, 0);
}
__device__ __forceinline__ f32x4 mfma_bf(bf8 a, bf8 b, f32x4 c){
  return __builtin_amdgcn_mfma_f32_16x16x32_bf16(a, b, c, 0, 0, 0);
}
__device__ __forceinline__ h8 ldw8(const float* p){
  f32x4 a = *(const f32x4*)p, b = *(const f32x4*)(p+4);
  h8 v;
  #pragma unroll
  for (int j=0;j<4;j++){ v[j] = (half_t)a[j]; v[4+j] = (half_t)b[j]; }
  return v;
}

// ---- fused prep + weight-convert + EF table --------------------------------------
__global__ __launch_bounds__(256) void k_prep(const float* __restrict__ x,
    const int* __restrict__ dst,
    int* __restrict__ typ, int* __restrict__ mlist, int* __restrict__ cnt,
    int* __restrict__ deg, ushort* __restrict__ Hb,
    const float* wq, const float* wk, const float* wv,
    const float* w1, const float* w2, const float* wih, const float* whh,
    const float* __restrict__ op_emb,
    ushort* oqkv, ushort* o1, ushort* o2, ushort* oih, ushort* ohh,
    ushort* __restrict__ EF,
    int N, int E){
  int i = blockIdx.x*256 + threadIdx.x;
  int total = gridDim.x*256;
  if (i < N){
    const float* xr = x + (size_t)i*16;
    int t = 0;
    #pragma unroll
    for (int j=0;j<16;j++) if (xr[j] > 0.5f) t = j;
    typ[i] = t;
    if (t < 2){
      int p = atomicAdd(cnt, 1);
      mlist[p] = i;
    }
  }
  if (i < E) atomicAdd(&deg[dst[i]], 1);
  uint2 z2; z2.x = 0u; z2.y = 0u;
  for (int j = i; j < N*32; j += total) ((uint2*)Hb)[j] = z2;
  for (int j=i; j<16384; j+=total){
    oqkv[j]       = f2bf(wq[j]);
    oqkv[16384+j] = f2bf(wk[j]);
    oqkv[32768+j] = f2bf(wv[j]);
    o1[j] = f2bf(w1[j]);
    o2[j] = f2bf(w2[j]);
  }
  for (int j=i; j<49152; j+=total){ oih[j]=f2bf(wih[j]); ohh[j]=f2bf(whh[j]); }
  for (int idx=i; idx<512*128; idx+=total){
    int r = idx >> 7, d = idx & 127;
    int et = r >> 4, op = r & 15;
    int j = d >> 1;
    float inv = __expf(-0.1439115683f * (float)j);   // 10000^(-j/64)
    float ang = (float)et * inv;
    float v = (d & 1) ? __cosf(ang) : __sinf(ang);
    EF[idx] = f2bf(v + op_emb[op*128 + d]);
  }
}

// ---- generic bf16 MFMA GEMM: C[M,N] = act(A[M,128] @ B[N,128]^T + bias) --------
template<int RELU, int HASBIAS>
__global__ __launch_bounds__(256) void k_gemm(
    const ushort* __restrict__ A, const ushort* __restrict__ B,
    const float* __restrict__ bias, ushort* __restrict__ C, int M, int N){
  int lane = threadIdx.x & 63, wv = threadIdx.x >> 6;
  int tM = blockIdx.x*64 + (wv>>1)*32;
  int tN = blockIdx.y*64 + (wv&1)*32;
  int r16 = lane & 15, kg = (lane>>4)*8;
  f32x4 acc[2][2];
  #pragma unroll
  for (int i=0;i<2;i++)
    #pragma unroll
    for (int j=0;j<2;j++) acc[i][j] = (f32x4)0.0f;
  #pragma unroll
  for (int k0=0;k0<128;k0+=32){
    bf8 a[2], b[2];
    #pragma unroll
    for (int i=0;i<2;i++){
      int row = tM + i*16 + r16; if (row > M-1) row = M-1;
      a[i] = *(const bf8*)(A + (size_t)row*128 + k0 + kg);
    }
    #pragma unroll
    for (int j=0;j<2;j++){
      int col = tN + j*16 + r16;
      b[j] = *(const bf8*)(B + (size_t)col*128 + k0 + kg);
    }
    #pragma unroll
    for (int i=0;i<2;i++)
      #pragma unroll
      for (int j=0;j<2;j++)
        acc[i][j] = __builtin_amdgcn_mfma_f32_16x16x32_bf16(a[i], b[j], acc[i][j], 0, 0, 0);
  }
  #pragma unroll
  for (int i=0;i<2;i++)
    #pragma unroll
    for (int j=0;j<2;j++){
      int col = tN + j*16 + r16;
      float bs = HASBIAS ? bias[col] : 0.0f;
      #pragma unroll
      for (int q=0;q<4;q++){
        int row = tM + i*16 + (lane>>4)*4 + q;
        if (row < M){
          float v = acc[i][j][q] + bs;
          if (RELU) v = fmaxf(v, 0.0f);
          C[(size_t)row*N + col] = f2bf(v);
        }
      }
    }
}

// ---- pipelined swapped-MFMA 2-layer GRU encoder (f16 x-staging) -----------------
__global__ __launch_bounds__(512, 1) void k_enc4(
    const float* __restrict__ sim_res, const int* __restrict__ seqlen,
    const float* __restrict__ Wih0, const float* __restrict__ Whh0,
    const float* __restrict__ bih0, const float* __restrict__ bhh0,
    const float* __restrict__ Wih1, const float* __restrict__ Whh1,
    const float* __restrict__ bih1, const float* __restrict__ bhh1,
    const int* __restrict__ mlist, const int* __restrict__ cntp,
    ushort* __restrict__ Hb){
  int C = *cntp;
  int base = blockIdx.x * 16;
  if (C == 0 || base >= C) return;
  int tid = threadIdx.x;
  int w = tid >> 6, l = tid & 63;
  int node = l & 15, hi = l >> 4;
  int grp = w >> 2;          // 0 = layer 0 group, 1 = layer 1 group
  int ws  = w & 3;           // hidden-slice owner within group

  __shared__ int nod[16];
  __shared__ __align__(16) ushort Xh[16*32*32];               // f16, 32 KB
  __shared__ __align__(16) ushort H0h[2][16*64], H1h[2][16*64];

  if (tid < 16){
    int idx = base + tid;
    nod[tid] = mlist[idx < C ? idx : C-1];
  }
  for (int i = tid; i < 16*64; i += 512){
    H0h[0][i] = 0; H0h[1][i] = 0; H1h[0][i] = 0; H1h[1][i] = 0;
  }
  __syncthreads();   // nod ready

  // stage x as f16: 2048 chunks of 16B. chunk m = [node(4b)][t(5b)][c(2b)];
  // LDS logical chunk c holds source chunk c^(node&3).
  for (int m = tid; m < 2048; m += 512){
    int nm = m >> 7, rem = m & 127, tt = rem >> 2, c = rem & 3;
    int cs = c ^ (nm & 3);
    const float* s = sim_res + (size_t)nod[nm]*1024 + tt*32 + cs*8;
    f32x4 a = *(const f32x4*)s, b = *(const f32x4*)(s+4);
    h8 v;
    #pragma unroll
    for (int j=0;j<4;j++){ v[j] = (half_t)a[j]; v[4+j] = (half_t)b[j]; }
    *(h8*)((char*)Xh + m*16) = v;
  }

  int rr = 16*ws + node;
  h8 zf;
  #pragma unroll
  for (int j=0;j<8;j++) zf[j] = (half_t)0.f;
  h8 Ai_r[2] = {zf, zf}, Ai_z[2] = {zf, zf}, Ai_n[2] = {zf, zf};
  h8 Ah_r[2], Ah_z[2], Ah_n[2];
  if (grp == 0){
    Ai_r[0] = ldw8(Wih0 + (size_t)rr*32        + hi*8);
    Ai_z[0] = ldw8(Wih0 + (size_t)(64+rr)*32   + hi*8);
    Ai_n[0] = ldw8(Wih0 + (size_t)(128+rr)*32  + hi*8);
    #pragma unroll
    for (int s=0;s<2;s++){
      Ah_r[s] = ldw8(Whh0 + (size_t)rr*64       + s*32 + hi*8);
      Ah_z[s] = ldw8(Whh0 + (size_t)(64+rr)*64  + s*32 + hi*8);
      Ah_n[s] = ldw8(Whh0 + (size_t)(128+rr)*64 + s*32 + hi*8);
    }
  } else {
    #pragma unroll
    for (int s=0;s<2;s++){
      Ai_r[s] = ldw8(Wih1 + (size_t)rr*64       + s*32 + hi*8);
      Ai_z[s] = ldw8(Wih1 + (size_t)(64+rr)*64  + s*32 + hi*8);
      Ai_n[s] = ldw8(Wih1 + (size_t)(128+rr)*64 + s*32 + hi*8);
      Ah_r[s] = ldw8(Whh1 + (size_t)rr*64       + s*32 + hi*8);
      Ah_z[s] = ldw8(Whh1 + (size_t)(64+rr)*64  + s*32 + hi*8);
      Ah_n[s] = ldw8(Whh1 + (size_t)(128+rr)*64 + s*32 + hi*8);
    }
  }
  const float* bi = grp ? bih1 : bih0;
  const float* bh = grp ? bhh1 : bhh0;
  float br[4], bz[4], bni[4], bnh[4];
  #pragma unroll
  for (int q=0;q<4;q++){
    int row = 16*ws + hi*4 + q;
    br[q]  = bi[row]      + bh[row];
    bz[q]  = bi[64+row]   + bh[64+row];
    bni[q] = bi[128+row];
    bnh[q] = bh[128+row];
  }

  int T = *seqlen; if (T > 32) T = 32; if (T < 0) T = 0;
  float hm[4] = {0.f, 0.f, 0.f, 0.f};

  const int swz = (node & 7) << 4;
  const int wo  = node * 128;
  const int wba = 32*ws + 8*hi;
  const int rd0 = wo + ((16*hi) ^ swz);
  const int rd1 = wo + ((64 + 16*hi) ^ swz);
  const int xoff = node*2048 + ((hi*16) ^ ((node & 3) << 4));  // byte offset; + t*64
  const char* xbase = (const char*)Xh;

  __syncthreads();   // Xh + zeroed state buffers ready

  for (int k = 0; k <= T; ++k){
    int cur = k & 1;
    bool act = grp ? (k >= 1) : (k < T);
    if (act){
      h8 in0 = zf, in1 = zf, st0, st1;
      if (grp == 0){
        in0 = *(const h8*)(xbase + xoff + k*64);
        st0 = *(const h8*)((const char*)H0h[cur] + rd0);
        st1 = *(const h8*)((const char*)H0h[cur] + rd1);
      } else {
        in0 = *(const h8*)((const char*)H0h[cur] + rd0);
        in1 = *(const h8*)((const char*)H0h[cur] + rd1);
        st0 = *(const h8*)((const char*)H1h[cur] + rd0);
        st1 = *(const h8*)((const char*)H1h[cur] + rd1);
      }
      f32x4 ar = {br[0],br[1],br[2],br[3]};
      f32x4 az = {bz[0],bz[1],bz[2],bz[3]};
      f32x4 an = {bni[0],bni[1],bni[2],bni[3]};
      f32x4 hn = {bnh[0],bnh[1],bnh[2],bnh[3]};
      __builtin_amdgcn_s_setprio(1);
      ar = mfma_f16(Ai_r[0], in0, ar);
      az = mfma_f16(Ai_z[0], in0, az);
      an = mfma_f16(Ai_n[0], in0, an);
      if (grp){
        ar = mfma_f16(Ai_r[1], in1, ar);
        az = mfma_f16(Ai_z[1], in1, az);
        an = mfma_f16(Ai_n[1], in1, an);
      }
      ar = mfma_f16(Ah_r[0], st0, ar); ar = mfma_f16(Ah_r[1], st1, ar);
      az = mfma_f16(Ah_z[0], st0, az); az = mfma_f16(Ah_z[1], st1, az);
      hn = mfma_f16(Ah_n[0], st0, hn); hn = mfma_f16(Ah_n[1], st1, hn);
      __builtin_amdgcn_s_setprio(0);
      #pragma unroll
      for (int q=0;q<4;q++){
        float r = sigmoidf_(ar[q]);
        float z = sigmoidf_(az[q]);
        float n = tanhf_(an[q] + r*hn[q]);
        hm[q] = (1.f - z)*n + z*hm[q];
      }
      char* outb = grp ? (char*)H1h[cur^1] : (char*)H0h[cur^1];
      *(uint*)(outb + wo + ( wba      ^ swz)) = pkhalf(hm[0], hm[1]);
      *(uint*)(outb + wo + ((wba + 4) ^ swz)) = pkhalf(hm[2], hm[3]);
    }
    __syncthreads();
  }

  if (base + node < C){
    int nd = nod[node];
    int off = grp ? 64 : 0;
    #pragma unroll
    for (int q=0;q<4;q++){
      int j = off + 16*ws + hi*4 + q;
      Hb[(size_t)nd*128 + j] = f2bf(hm[q]);
    }
  }
}

// ---- CSR scan: thread-coarsened single pass (1 barrier) ---------------------------
__global__ __launch_bounds__(1024) void k_scan(const int* __restrict__ deg,
    int* __restrict__ rowptr, int* __restrict__ cursor, int N){
  __shared__ int wsum[16];
  int tid = threadIdx.x, lane = tid & 63, wid = tid >> 6;
  int CH = (N + 1023) >> 10;
  int start = tid * CH;
  int local = 0;
  for (int j=0;j<CH;j++){ int i = start+j; if (i < N) local += deg[i]; }
  int x = local;
  #pragma unroll
  for (int off=1; off<64; off<<=1){
    int t = __shfl_up(x, off, 64);
    if (lane >= off) x += t;
  }
  if (lane == 63) wsum[wid] = x;
  __syncthreads();
  int woff = 0;
  for (int w2=0; w2<wid; ++w2) woff += wsum[w2];
  int run = woff + x - local;
  for (int j=0;j<CH;j++){
    int i = start+j;
    if (i < N){ rowptr[i] = run; cursor[i] = run; run += deg[i]; }
  }
  if (tid == 1023) rowptr[N] = run;
}

__global__ __launch_bounds__(256) void k_scatter(const int* __restrict__ src,
    const int* __restrict__ dst, const int* __restrict__ etype, const int* __restrict__ typ,
    int* __restrict__ cursor, int* __restrict__ es_src, int* __restrict__ es_tab, int E){
  int e = blockIdx.x*256 + threadIdx.x;
  if (e < E){
    int d = dst[e];
    int pos = atomicAdd(&cursor[d], 1);
    es_src[pos] = src[e];
    es_tab[pos] = etype[e]*16 + typ[d];
  }
}

// ---- attention: one wave per dst node, online softmax, 4-edge unrolled -----------
__global__ __launch_bounds__(256) void k_attn(
    const uint* __restrict__ QKV, const uint* __restrict__ KVT,
    const int* __restrict__ rowptr, const int* __restrict__ es_src, const int* __restrict__ es_tab,
    uint* __restrict__ aggr, int N){
  int w = threadIdx.x >> 6, lane = threadIdx.x & 63;
  int dst = blockIdx.x*4 + w;
  if (dst >= N) return;
  uint qu = QKV[(size_t)dst*192 + lane];
  const float scale = 0.08838834764831845f;  // 1/sqrt(128)
  float q0 = bfl(qu)*scale, q1 = bfh(qu)*scale;
  int s0 = rowptr[dst], s1 = rowptr[dst+1];
  float m = -1e30f, den = 0.f, a0 = 0.f, a1 = 0.f;
  int p = s0;
  for (; p + 4 <= s1; p += 4){
    int se[4], te[4];
    #pragma unroll
    for (int e=0;e<4;e++){ se[e] = es_src[p+e]; te[e] = es_tab[p+e]; }
    uint ku[4], kt[4], vu[4], vt[4];
    #pragma unroll
    for (int e=0;e<4;e++){
      ku[e] = QKV[(size_t)se[e]*192 + 64 + lane];
      kt[e] = KVT[(size_t)te[e]*128 + lane];
      vu[e] = QKV[(size_t)se[e]*192 + 128 + lane];
      vt[e] = KVT[(size_t)te[e]*128 + 64 + lane];
    }
    float s[4];
    #pragma unroll
    for (int e=0;e<4;e++)
      s[e] = q0*(bfl(ku[e])+bfl(kt[e])) + q1*(bfh(ku[e])+bfh(kt[e]));
    #pragma unroll
    for (int off=32; off; off>>=1){
      #pragma unroll
      for (int e=0;e<4;e++) s[e] += __shfl_xor(s[e], off);
    }
    float nm = fmaxf(fmaxf(m, fmaxf(s[0], s[1])), fmaxf(s[2], s[3]));
    float c  = __expf(m - nm);
    float pw[4];
    #pragma unroll
    for (int e=0;e<4;e++) pw[e] = __expf(s[e] - nm);
    den = den*c + pw[0] + pw[1] + pw[2] + pw[3];
    a0 = a0*c; a1 = a1*c;
    #pragma unroll
    for (int e=0;e<4;e++){
      a0 += pw[e]*(bfl(vu[e])+bfl(vt[e]));
      a1 += pw[e]*(bfh(vu[e])+bfh(vt[e]));
    }
    m = nm;
  }
  for (; p < s1; ++p){
    int src = es_src[p], tb = es_tab[p];
    uint ku = QKV[(size_t)src*192 + 64 + lane],  kt = KVT[(size_t)tb*128 + lane];
    uint vu = QKV[(size_t)src*192 + 128 + lane], vt = KVT[(size_t)tb*128 + 64 + lane];
    float s = q0*(bfl(ku)+bfl(kt)) + q1*(bfh(ku)+bfh(kt));
    #pragma unroll
    for (int off=32; off; off>>=1) s += __shfl_xor(s, off);
    float nm = fmaxf(m, s);
    float c  = __expf(m - nm);
    float pw = __expf(s - nm);
    den = den*c + pw;
    a0  = a0*c + pw*(bfl(vu)+bfl(vt));
    a1  = a1*c + pw*(bfh(vu)+bfh(vt));
    m = nm;
  }
  float inv = 1.0f/(den + 1e-9f);
  a0 *= inv; a1 *= inv;
  aggr[(size_t)dst*64 + lane] = ((uint)f2bf(a1) << 16) | (uint)f2bf(a0);
}

// ---- fused MLP1 + MLP2 + GRU cell — 32 nodes/block, 8 waves × 16 cols -------------
// h-state carried in bf16 only (Hb); final round writes f32 d_out directly.
// NOTE: Hb_io is read (entry, pre-barrier) and written (epilogue, post-barrier);
// barrier 1 guarantees all entry loads complete before any epilogue write.
__global__ __launch_bounds__(512, 2) void k_fused(
    const ushort* __restrict__ Ag,
    const ushort* __restrict__ W1b, const float* __restrict__ b1,
    const ushort* __restrict__ W2b, const float* __restrict__ b2,
    const ushort* __restrict__ Wih, const ushort* __restrict__ Whh,
    const float* __restrict__ bih, const float* __restrict__ bhh,
    ushort* Hb_io, float* Fout, int M){
  int lane = threadIdx.x & 63, w = threadIdx.x >> 6;   // w: 0..7, 16 cols each
  int nb = blockIdx.x * 32;
  int r16 = lane & 15, kq = lane >> 4;
  const int col = w*16 + r16;                          // 0..127

  __shared__ __align__(16) ushort T[32*128];   // 8 KB swizzled intermediate

  // entry loads (A-operands shared across phases)
  bf8 agld[2][4], ahld[2][4];
  #pragma unroll
  for (int i=0;i<2;i++){
    int grow = nb + i*16 + r16; if (grow > M-1) grow = M-1;
    #pragma unroll
    for (int ks=0;ks<4;ks++){
      agld[i][ks] = *(const bf8*)(Ag    + (size_t)grow*128 + ks*32 + kq*8);
      ahld[i][ks] = *(const bf8*)(Hb_io + (size_t)grow*128 + ks*32 + kq*8);
    }
  }
  float hprev[2][4];
  #pragma unroll
  for (int i=0;i<2;i++)
    #pragma unroll
    for (int q=0;q<4;q++){
      int node = nb + i*16 + kq*4 + q;
      hprev[i][q] = bfl((uint)Hb_io[(size_t)(node < M ? node : M-1)*128 + col]);
    }

  // ---------- phase 1: T = relu(Ag @ W1^T + b1) ----------
  {
    f32x4 a0 = (f32x4)0.0f, a1v = (f32x4)0.0f;
    #pragma unroll
    for (int ks=0; ks<4; ++ks){
      bf8 wb = *(const bf8*)(W1b + (size_t)col*128 + ks*32 + kq*8);
      a0  = mfma_bf(agld[0][ks], wb, a0);
      a1v = mfma_bf(agld[1][ks], wb, a1v);
    }
    float bs = b1[col];
    #pragma unroll
    for (int q=0;q<4;q++){
      int row0 = kq*4 + q, row1 = 16 + kq*4 + q;
      *(ushort*)((char*)T + ((row0*256 + col*2) ^ ((row0&7)<<4))) = f2bf(fmaxf(a0[q]  + bs, 0.0f));
      *(ushort*)((char*)T + ((row1*256 + col*2) ^ ((row1&7)<<4))) = f2bf(fmaxf(a1v[q] + bs, 0.0f));
    }
  }
  __syncthreads();

  // ---------- phase 2: X = T @ W2^T + b2 ----------
  {
    f32x4 a0 = (f32x4)0.0f, a1v = (f32x4)0.0f;
    #pragma unroll
    for (int ks=0; ks<4; ++ks){
      bf8 wb = *(const bf8*)(W2b + (size_t)col*128 + ks*32 + kq*8);
      bf8 ax0, ax1;
      {
        int row = r16;
        ax0 = *(const bf8*)((const char*)T + row*256 + ((ks*64 + kq*16) ^ ((row&7)<<4)));
      }
      {
        int row = 16 + r16;
        ax1 = *(const bf8*)((const char*)T + row*256 + ((ks*64 + kq*16) ^ ((row&7)<<4)));
      }
      a0  = mfma_bf(ax0, wb, a0);
      a1v = mfma_bf(ax1, wb, a1v);
    }
    __syncthreads();   // all T reads complete before overwrite
    float bs = b2[col];
    #pragma unroll
    for (int q=0;q<4;q++){
      int row0 = kq*4 + q, row1 = 16 + kq*4 + q;
      *(ushort*)((char*)T + ((row0*256 + col*2) ^ ((row0&7)<<4))) = f2bf(a0[q]  + bs);
      *(ushort*)((char*)T + ((row1*256 + col*2) ^ ((row1&7)<<4))) = f2bf(a1v[q] + bs);
    }
  }
  __syncthreads();

  // ---------- phase 3: GRU gates ----------
  f32x4 ar[2], az[2], ani[2], anh[2];
  #pragma unroll
  for (int i=0;i<2;i++){
    ar[i] = (f32x4)0.0f; az[i] = (f32x4)0.0f;
    ani[i] = (f32x4)0.0f; anh[i] = (f32x4)0.0f;
  }
  #pragma unroll
  for (int ks=0; ks<4; ++ks){
    int off = ks*32 + kq*8;
    bf8 wri = *(const bf8*)(Wih + (size_t)col*128       + off);
    bf8 wrh = *(const bf8*)(Whh + (size_t)col*128       + off);
    bf8 wzi = *(const bf8*)(Wih + (size_t)(128+col)*128 + off);
    bf8 wzh = *(const bf8*)(Whh + (size_t)(128+col)*128 + off);
    bf8 wni = *(const bf8*)(Wih + (size_t)(256+col)*128 + off);
    bf8 wnh = *(const bf8*)(Whh + (size_t)(256+col)*128 + off);
    bf8 ax0, ax1;
    {
      int row = r16;
      ax0 = *(const bf8*)((const char*)T + row*256 + ((ks*64 + kq*16) ^ ((row&7)<<4)));
    }
    {
      int row = 16 + r16;
      ax1 = *(const bf8*)((const char*)T + row*256 + ((ks*64 + kq*16) ^ ((row&7)<<4)));
    }
    ar[0]  = mfma_bf(ax0,         wri, ar[0]);
    ar[0]  = mfma_bf(ahld[0][ks], wrh, ar[0]);
    az[0]  = mfma_bf(ax0,         wzi, az[0]);
    az[0]  = mfma_bf(ahld[0][ks], wzh, az[0]);
    ani[0] = mfma_bf(ax0,         wni, ani[0]);
    anh[0] = mfma_bf(ahld[0][ks], wnh, anh[0]);
    ar[1]  = mfma_bf(ax1,         wri, ar[1]);
    ar[1]  = mfma_bf(ahld[1][ks], wrh, ar[1]);
    az[1]  = mfma_bf(ax1,         wzi, az[1]);
    az[1]  = mfma_bf(ahld[1][ks], wzh, az[1]);
    ani[1] = mfma_bf(ax1,         wni, ani[1]);
    anh[1] = mfma_bf(ahld[1][ks], wnh, anh[1]);
  }
  // epilogue: gates + in-lane h update
  float br_  = bih[col]     + bhh[col];
  float bz_  = bih[128+col] + bhh[128+col];
  float bni_ = bih[256+col];
  float bnh_ = bhh[256+col];
  #pragma unroll
  for (int i=0;i<2;i++)
    #pragma unroll
    for (int q=0;q<4;q++){
      int node = nb + i*16 + kq*4 + q;
      if (node < M){
        float r = sigmoidf_(ar[i][q] + br_);
        float z = sigmoidf_(az[i][q] + bz_);
        float n = tanhf_(ani[i][q] + bni_ + r*(anh[i][q] + bnh_));
        float h = hprev[i][q];
        float o = (1.f - z)*n + z*h;
        Hb_io[(size_t)node*128 + col] = f2bf(o);
        if (Fout) Fout[(size_t)node*128 + col] = o;
      }
    }
}

extern "C" void kernel_launch(void* const* d_in, const int* in_sizes, int n_in,
                              void* d_out, int out_size, void* d_ws, size_t ws_size,
                              hipStream_t stream){
  const float* x       = (const float*)d_in[0];
  const int*   ei      = (const int*)d_in[1];
  const int*   etype   = (const int*)d_in[2];
  const float* sim_res = (const float*)d_in[3];
  const int*   seqlen  = (const int*)d_in[4];
  const float* eWih0 = (const float*)d_in[5];
  const float* eWhh0 = (const float*)d_in[6];
  const float* ebih0 = (const float*)d_in[7];
  const float* ebhh0 = (const float*)d_in[8];
  const float* eWih1 = (const float*)d_in[9];
  const float* eWhh1 = (const float*)d_in[10];
  const float* ebih1 = (const float*)d_in[11];
  const float* ebhh1 = (const float*)d_in[12];
  const float* Wq = (const float*)d_in[13];
  const float* Wk = (const float*)d_in[14];
  const float* Wv = (const float*)d_in[15];
  const float* op_emb = (const float*)d_in[16];
  const float* W1 = (const float*)d_in[17];
  const float* b1 = (const float*)d_in[18];
  const float* W2 = (const float*)d_in[19];
  const float* b2 = (const float*)d_in[20];
  const float* gWih = (const float*)d_in[21];
  const float* gWhh = (const float*)d_in[22];
  const float* gbih = (const float*)d_in[23];
  const float* gbhh = (const float*)d_in[24];

  const int N = in_sizes[0] / 16;
  const int E = in_sizes[2];

  char* p = (char*)d_ws;
  auto take = [&](size_t b)->void*{ void* r = (void*)p; p += (b + 255) & ~(size_t)255; return r; };

  ushort* Hb    = (ushort*)take((size_t)N*128*2);
  ushort* QKV   = (ushort*)take((size_t)N*384*2);
  ushort* Ag    = (ushort*)take((size_t)N*128*2);
  ushort* EF    = (ushort*)take((size_t)512*128*2);
  ushort* KVtab = (ushort*)take((size_t)512*256*2);
  ushort* wqkv  = (ushort*)take((size_t)3*16384*2);   // [wq | wk | wv] rows
  ushort* w1_b  = (ushort*)take((size_t)16384*2);
  ushort* w2_b  = (ushort*)take((size_t)16384*2);
  ushort* wih_b = (ushort*)take((size_t)49152*2);
  ushort* whh_b = (ushort*)take((size_t)49152*2);
  int* typ    = (int*)take((size_t)N*4);
  int* mlist  = (int*)take((size_t)N*4);
  int* cnt    = (int*)take(256);
  int* deg    = (int*)take((size_t)N*4);
  int* rowptr = (int*)take((size_t)(N+1)*4);
  int* cursor = (int*)take((size_t)N*4);
  int* es_src = (int*)take((size_t)E*4);
  int* es_tab = (int*)take((size_t)E*4);

  hipMemsetAsync(cnt, 0, 4, stream);
  hipMemsetAsync(deg, 0, (size_t)N*4, stream);

  int gE = (E + 255) / 256;
  k_prep<<<gE, 256, 0, stream>>>(x, ei + E, typ, mlist, cnt, deg, Hb,
                                 Wq, Wk, Wv, W1, W2, gWih, gWhh, op_emb,
                                 wqkv, w1_b, w2_b, wih_b, whh_b, EF, N, E);
  k_gemm<0,0><<<dim3(8,4), 256, 0, stream>>>(EF, wqkv + 16384, nullptr, KVtab, 512, 256);
  k_enc4<<<(N+15)/16, 512, 0, stream>>>(sim_res, seqlen, eWih0, eWhh0, ebih0, ebhh0,
                                        eWih1, eWhh1, ebih1, ebhh1, mlist, cnt, Hb);
  k_scan<<<1, 1024, 0, stream>>>(deg, rowptr, cursor, N);
  k_scatter<<<gE, 256, 0, stream>>>(ei, ei + E, etype, typ, cursor, es_src, es_tab, E);

  dim3 gq((N+63)/64, 6);   // fused QKV: N_out = 384
  for (int r=0; r<2; ++r){
    k_gemm<0,0><<<gq, 256, 0, stream>>>(Hb, wqkv, nullptr, QKV, N, 384);
    k_attn<<<(N+3)/4, 256, 0, stream>>>((const uint*)QKV, (const uint*)KVtab,
                                        rowptr, es_src, es_tab, (uint*)Ag, N);
    float* fout = (r == 1) ? (float*)d_out : nullptr;
    k_fused<<<(N+31)/32, 512, 0, stream>>>(Ag, w1_b, b1, w2_b, b2,
                                           wih_b, whh_b, gbih, gbhh,
                                           Hb, fout, N);
  }
}